// Round 13
// baseline (309.363 us; speedup 1.0000x reference)
//
#include <hip/hip_runtime.h>

#define NWIN 4096
#define DIM 96
#define HEADS 6
#define NTOK 64
#define WPB 4  // windows per block; grid = NWIN/WPB = 1024

typedef __bf16 bf16x8 __attribute__((ext_vector_type(8)));
typedef __bf16 bf16x4 __attribute__((ext_vector_type(4)));
typedef short  s16x4  __attribute__((ext_vector_type(4)));
typedef float  f32x4  __attribute__((ext_vector_type(4)));

// d_ws layout
#define WS_QKVW 0                   // 288*96 bf16 = 55296 B
#define WS_PROJW 55296              // 96*96 bf16  = 18432 B
#define WS_BIAS 73728               // 6*16*64 float4 = 98304 B (frag-ordered)
#define WS_TOTAL 172032

__device__ __forceinline__ f32x4 mfma32(bf16x8 a, bf16x8 b, f32x4 c) {
  return __builtin_amdgcn_mfma_f32_16x16x32_bf16(a, b, c, 0, 0, 0);
}
// K=16 MFMA. Fragment alignment facts (verified r7-r9):
//  * A/B fragment lane(l16,lq) holds row/col=l16, k=4*lq+e  — identical to
//    the W*X^T D-fragment (row=4lq+r, col=l16), so K,Q stay in registers.
//  * QK^T output s[a] = S[q=l16][kv=16a+4lq+r] — IS the PV A-frag chunk a.
//  * V-phase D-frag for mt=a IS the PV B-frag chunk a.
//  => K,Q,V,P all stay in registers; no LDS in the attention core.
__device__ __forceinline__ f32x4 mfma16k(bf16x4 a, bf16x4 b, f32x4 c) {
  return __builtin_amdgcn_mfma_f32_16x16x16bf16_1k(
      __builtin_bit_cast(s16x4, a), __builtin_bit_cast(s16x4, b), c, 0, 0, 0);
}

__device__ __forceinline__ bf16x8 cvt8(const float* p) {
  const float4* q = (const float4*)p;
  float4 a = q[0];
  float4 b = q[1];
  bf16x8 r;
  r[0] = (__bf16)a.x; r[1] = (__bf16)a.y; r[2] = (__bf16)a.z; r[3] = (__bf16)a.w;
  r[4] = (__bf16)b.x; r[5] = (__bf16)b.y; r[6] = (__bf16)b.z; r[7] = (__bf16)b.w;
  return r;
}

// Pre-pass: weights -> bf16; bias gathered into MFMA-fragment order:
// bias[((h*16 + bq*4 + a)*64 + lane)*4 + r] = rpb[rpi[qrow*64+kcol]*6+h]
// with qrow = 16*bq + (lane&15), kcol = 16*a + 4*(lane>>4) + r.
__global__ void prep_kernel(const float* __restrict__ qkv_w,
                            const float* __restrict__ proj_w,
                            const float* __restrict__ rpb,
                            const int* __restrict__ rpi,
                            char* __restrict__ ws) {
  int i = blockIdx.x * blockDim.x + threadIdx.x;
  __bf16* qw = (__bf16*)(ws + WS_QKVW);
  __bf16* pw = (__bf16*)(ws + WS_PROJW);
  float* bias = (float*)(ws + WS_BIAS);
  if (i < 288 * 96) qw[i] = (__bf16)qkv_w[i];
  int j = i - 288 * 96;
  if (j >= 0 && j < 96 * 96) pw[j] = (__bf16)proj_w[j];
  int t = i - (288 * 96 + 96 * 96);
  if (t >= 0 && t < HEADS * 16 * 64 * 4) {
    int r = t & 3;
    int lane = (t >> 2) & 63;
    int ba = (t >> 8) & 15;
    int h = t >> 12;
    int bq = ba >> 2, a = ba & 3;
    int l16 = lane & 15, lq = lane >> 4;
    int qrow = 16 * bq + l16;
    int kcol = 16 * a + 4 * lq + r;
    bias[t] = rpb[rpi[qrow * 64 + kcol] * HEADS + h];
  }
}

// r13: r9's per-window body (measured 60 arch VGPR, the spill cliff is ~64
// under launch_bounds(384,4) — r11/r12 lesson: ZERO cross-window register
// state allowed), looped over WPB=4 windows. Grid 1024 -> 4 blocks/CU
// resident from t=0 (24 waves/CU vs r9's observed 9.6): attacks the
// cross-round invariant that r4/r8/r9 all plateau at ~50 windows/us from
// per-window latency x low co-residency.
// LDS: xfrag 12288 B + ao 13312 B separate (no overlay) so stage(i+1)
// overlaps proj(i); 2 barriers/window. Hazards: xfrag reads end at
// frontend(i) < B_ao < stage(i+1) writes; ao reads end at proj(i) < B_x <
// attention(i+1) writes.
template <bool USE_WS>
__global__ __launch_bounds__(384, 4) void win_attn(
    const float* __restrict__ x,
    const int* __restrict__ rpi,
    const float* __restrict__ qkv_w,
    const float* __restrict__ qkv_b,
    const float* __restrict__ proj_w,
    const float* __restrict__ proj_b,
    const float* __restrict__ rpb,
    const char* __restrict__ ws,
    float* __restrict__ out) {
  __shared__ __align__(16) __bf16 xfrag[6144];   // 12 frags * 512 bf16
  __shared__ __align__(16) __bf16 ao[64 * 104];  // 13312 B

  const int tid = (int)threadIdx.x;
  const int wv = tid >> 6;
  const int lane = tid & 63;
  const int l16 = lane & 15;
  const int lq = lane >> 4;
  const int base = (int)blockIdx.x * WPB;

  const __bf16* qwb = (const __bf16*)(ws + WS_QKVW);
  const __bf16* pwb = (const __bf16*)(ws + WS_PROJW);
  const float4* bias4 = (const float4*)(ws + WS_BIAS) + (wv << 10);

  bf16x4 kb[4], qv4[4], vb4[4];

  // ---- prologue: stage window base+0 (wave wv owns frags 2wv, 2wv+1) ----
#pragma unroll
  for (int ff = 0; ff < 2; ++ff) {
    const int f = 2 * wv + ff;
    const int mt = f / 3, ks = f - 3 * mt;
    bf16x8 v = cvt8(x + (size_t)base * (NTOK * DIM) + (16 * mt + l16) * DIM +
                    32 * ks + 8 * lq);
    *(bf16x8*)(xfrag + (f * 64 + lane) * 8) = v;
  }
  __syncthreads();  // B_x(0)

  for (int i = 0; i < WPB; ++i) {
#define XV(mt, ks) \
  (*(const bf16x8*)(xfrag + (((mt) * 3 + (ks)) * 64 + lane) * 8))
    {  // K phase: D = Wk * X^T (D-frag = QK A-frag, stays in regs)
      const int frow = (HEADS + wv) * 16;
      bf16x8 wb[3];
#pragma unroll
      for (int ks = 0; ks < 3; ++ks) {
        if constexpr (USE_WS)
          wb[ks] = *(const bf16x8*)(qwb + (frow + l16) * 96 + 32 * ks + 8 * lq);
        else
          wb[ks] = cvt8(qkv_w + (frow + l16) * 96 + 32 * ks + 8 * lq);
      }
      const float4 kb4 = *(const float4*)(qkv_b + frow + 4 * lq);
      const float kbv[4] = {kb4.x, kb4.y, kb4.z, kb4.w};
#pragma unroll
      for (int mt = 0; mt < 4; ++mt) {
        f32x4 acc = {0.f, 0.f, 0.f, 0.f};
#pragma unroll
        for (int ks = 0; ks < 3; ++ks) acc = mfma32(wb[ks], XV(mt, ks), acc);
#pragma unroll
        for (int r = 0; r < 4; ++r) kb[mt][r] = (__bf16)(acc[r] + kbv[r]);
      }
    }
    {  // Q phase: D = Wq * X^T (scaled)
      const int frow = wv * 16;
      bf16x8 wb[3];
#pragma unroll
      for (int ks = 0; ks < 3; ++ks) {
        if constexpr (USE_WS)
          wb[ks] = *(const bf16x8*)(qwb + (frow + l16) * 96 + 32 * ks + 8 * lq);
        else
          wb[ks] = cvt8(qkv_w + (frow + l16) * 96 + 32 * ks + 8 * lq);
      }
      const float4 qb4 = *(const float4*)(qkv_b + frow + 4 * lq);
      const float qbv[4] = {qb4.x, qb4.y, qb4.z, qb4.w};
#pragma unroll
      for (int mt = 0; mt < 4; ++mt) {
        f32x4 acc = {0.f, 0.f, 0.f, 0.f};
#pragma unroll
        for (int ks = 0; ks < 3; ++ks) acc = mfma32(wb[ks], XV(mt, ks), acc);
#pragma unroll
        for (int r = 0; r < 4; ++r)
          qv4[mt][r] = (__bf16)((acc[r] + qbv[r]) * 0.25f);
      }
    }
    {  // V phase: D = X * Wv^T; D-frag mt=a IS the PV B-frag chunk a
      const int frow = (2 * HEADS + wv) * 16;
      bf16x8 wb[3];
#pragma unroll
      for (int ks = 0; ks < 3; ++ks) {
        if constexpr (USE_WS)
          wb[ks] = *(const bf16x8*)(qwb + (frow + l16) * 96 + 32 * ks + 8 * lq);
        else
          wb[ks] = cvt8(qkv_w + (frow + l16) * 96 + 32 * ks + 8 * lq);
      }
      const float vb = qkv_b[frow + l16];
#pragma unroll
      for (int mt = 0; mt < 4; ++mt) {
        f32x4 acc = {0.f, 0.f, 0.f, 0.f};
#pragma unroll
        for (int ks = 0; ks < 3; ++ks) acc = mfma32(XV(mt, ks), wb[ks], acc);
#pragma unroll
        for (int r = 0; r < 4; ++r) vb4[mt][r] = (__bf16)(acc[r] + vb);
      }
    }
#undef XV

    // ---- attention core: pure register dataflow (writes ao) ----
#pragma unroll
    for (int bq = 0; bq < 4; ++bq) {
      f32x4 s[4];
      if constexpr (USE_WS) {
#pragma unroll
        for (int a = 0; a < 4; ++a) {
          float4 t = bias4[(bq * 4 + a) * 64 + lane];
          s[a][0] = t.x; s[a][1] = t.y; s[a][2] = t.z; s[a][3] = t.w;
        }
      } else {
#pragma unroll
        for (int a = 0; a < 4; ++a)
#pragma unroll
          for (int r = 0; r < 4; ++r)
            s[a][r] = rpb[rpi[(16 * bq + l16) * 64 + 16 * a + 4 * lq + r] *
                              HEADS + wv];
      }

#pragma unroll
      for (int a = 0; a < 4; ++a) s[a] = mfma16k(kb[a], qv4[bq], s[a]);

      // unnormalized softmax (|logits|<<1 -> exp direct); tsum from the
      // bf16-rounded P so numerator/denominator match (r9 lesson)
      float tp[4];
      bf16x4 pa[4];
#pragma unroll
      for (int a = 0; a < 4; ++a) {
        float t0 = 0.f;
#pragma unroll
        for (int r = 0; r < 4; ++r) {
          const __bf16 pe = (__bf16)__expf(s[a][r]);
          pa[a][r] = pe;
          t0 += (float)pe;
        }
        tp[a] = t0;
      }
      float tsum = (tp[0] + tp[1]) + (tp[2] + tp[3]);
      tsum += __shfl_xor(tsum, 16);
      tsum += __shfl_xor(tsum, 32);  // rcp hides under PV

      f32x4 oacc = {0.f, 0.f, 0.f, 0.f};
#pragma unroll
      for (int a = 0; a < 4; ++a) oacc = mfma16k(pa[a], vb4[a], oacc);

      const float rv = 1.0f / tsum;  // normalize after PV (linearity)
#pragma unroll
      for (int r = 0; r < 4; ++r)
        ao[(16 * bq + 4 * lq + r) * 104 + 16 * wv + l16] =
            (__bf16)(oacc[r] * rv);
    }

    __syncthreads();  // B_ao: ao visible; xfrag reads (frontend) all done

    // ---- issue next window's x loads (latency hides under proj) ----
    float4 xr[4];
    if (i + 1 < WPB) {
      const float* xw = x + (size_t)(base + i + 1) * (NTOK * DIM);
#pragma unroll
      for (int ff = 0; ff < 2; ++ff) {
        const int f = 2 * wv + ff;
        const int mt = f / 3, ks = f - 3 * mt;
        const float4* p =
            (const float4*)(xw + (16 * mt + l16) * DIM + 32 * ks + 8 * lq);
        xr[2 * ff] = p[0];
        xr[2 * ff + 1] = p[1];
      }
    }

    // ---- proj (wpb loaded per-iteration: L1-hot, keeps live set flat) ----
    {
      bf16x8 wpb[3];
#pragma unroll
      for (int ks = 0; ks < 3; ++ks) {
        if constexpr (USE_WS)
          wpb[ks] =
              *(const bf16x8*)(pwb + (16 * wv + l16) * 96 + 32 * ks + 8 * lq);
        else
          wpb[ks] = cvt8(proj_w + (16 * wv + l16) * 96 + 32 * ks + 8 * lq);
      }
      const float pb2 = proj_b[16 * wv + l16];
      float* outw = out + (size_t)(base + i) * (NTOK * DIM);
#pragma unroll
      for (int mt = 0; mt < 4; ++mt) {
        f32x4 acc = {0.f, 0.f, 0.f, 0.f};
#pragma unroll
        for (int ks = 0; ks < 3; ++ks) {
          bf16x8 aa =
              *(const bf16x8*)(ao + (16 * mt + l16) * 104 + 32 * ks + 8 * lq);
          acc = mfma32(aa, wpb[ks], acc);
        }
#pragma unroll
        for (int r = 0; r < 4; ++r)
          outw[(16 * mt + 4 * lq + r) * 96 + 16 * wv + l16] = acc[r] + pb2;
      }
    }

    // ---- store staged x for window i+1 (disjoint from ao: no hazard) ----
    if (i + 1 < WPB) {
#pragma unroll
      for (int ff = 0; ff < 2; ++ff) {
        const int f = 2 * wv + ff;
        const float4 a = xr[2 * ff], c = xr[2 * ff + 1];
        bf16x8 v;
        v[0] = (__bf16)a.x; v[1] = (__bf16)a.y; v[2] = (__bf16)a.z;
        v[3] = (__bf16)a.w; v[4] = (__bf16)c.x; v[5] = (__bf16)c.y;
        v[6] = (__bf16)c.z; v[7] = (__bf16)c.w;
        *(bf16x8*)(xfrag + (f * 64 + lane) * 8) = v;
      }
      __syncthreads();  // B_x: xfrag(i+1) visible; proj done reading ao
    }
  }
}

extern "C" void kernel_launch(void* const* d_in, const int* in_sizes, int n_in,
                              void* d_out, int out_size, void* d_ws, size_t ws_size,
                              hipStream_t stream) {
  const float* x      = (const float*)d_in[0];
  const int*   rpi    = (const int*)d_in[1];
  const float* qkv_w  = (const float*)d_in[2];
  const float* qkv_b  = (const float*)d_in[3];
  const float* proj_w = (const float*)d_in[4];
  const float* proj_b = (const float*)d_in[5];
  const float* rpb    = (const float*)d_in[6];
  float* out = (float*)d_out;

  if (ws_size >= (size_t)WS_TOTAL) {
    prep_kernel<<<240, 256, 0, stream>>>(qkv_w, proj_w, rpb, rpi, (char*)d_ws);
    win_attn<true><<<NWIN / WPB, 384, 0, stream>>>(
        x, rpi, qkv_w, qkv_b, proj_w, proj_b, rpb, (const char*)d_ws, out);
  } else {
    win_attn<false><<<NWIN / WPB, 384, 0, stream>>>(
        x, rpi, qkv_w, qkv_b, proj_w, proj_b, rpb, (const char*)d_ws, out);
  }
}

// Round 14
// 86.837 us; speedup vs baseline: 3.5626x; 3.5626x over previous
//
#include <hip/hip_runtime.h>

#define NWIN 4096
#define DIM 96
#define HEADS 6
#define NTOK 64

typedef __bf16 bf16x8 __attribute__((ext_vector_type(8)));
typedef __bf16 bf16x4 __attribute__((ext_vector_type(4)));
typedef short  s16x4  __attribute__((ext_vector_type(4)));
typedef float  f32x4  __attribute__((ext_vector_type(4)));

// d_ws layout
#define WS_QKVW 0                   // 288*96 bf16 = 55296 B
#define WS_PROJW 55296              // 96*96 bf16  = 18432 B
#define WS_BIAS 73728               // 6*16*64 float4 = 98304 B (frag-ordered)
#define WS_TOTAL 172032

__device__ __forceinline__ f32x4 mfma32(bf16x8 a, bf16x8 b, f32x4 c) {
  return __builtin_amdgcn_mfma_f32_16x16x32_bf16(a, b, c, 0, 0, 0);
}
// K=16 MFMA. Fragment alignment facts (verified r7-r9):
//  * A/B fragment lane(l16,lq) holds row/col=l16, k=4*lq+e  — identical to
//    the W*X^T D-fragment (row=4lq+r, col=l16), so K,Q stay in registers.
//  * QK^T output s[a] = S[q=l16][kv=16a+4lq+r] — IS the PV A-frag chunk a.
//  * V-phase D-frag for mt=a IS the PV B-frag chunk a.
//  => K,Q,V,P all stay in registers; no LDS in the attention core.
__device__ __forceinline__ f32x4 mfma16k(bf16x4 a, bf16x4 b, f32x4 c) {
  return __builtin_amdgcn_mfma_f32_16x16x16bf16_1k(
      __builtin_bit_cast(s16x4, a), __builtin_bit_cast(s16x4, b), c, 0, 0, 0);
}

__device__ __forceinline__ bf16x8 cvt8(const float* p) {
  const float4* q = (const float4*)p;
  float4 a = q[0];
  float4 b = q[1];
  bf16x8 r;
  r[0] = (__bf16)a.x; r[1] = (__bf16)a.y; r[2] = (__bf16)a.z; r[3] = (__bf16)a.w;
  r[4] = (__bf16)b.x; r[5] = (__bf16)b.y; r[6] = (__bf16)b.z; r[7] = (__bf16)b.w;
  return r;
}

// Pre-pass: weights -> bf16; bias gathered into MFMA-fragment order:
// bias[((h*16 + bq*4 + a)*64 + lane)*4 + r] = rpb[rpi[qrow*64+kcol]*6+h]
// with qrow = 16*bq + (lane&15), kcol = 16*a + 4*(lane>>4) + r.
__global__ void prep_kernel(const float* __restrict__ qkv_w,
                            const float* __restrict__ proj_w,
                            const float* __restrict__ rpb,
                            const int* __restrict__ rpi,
                            char* __restrict__ ws) {
  int i = blockIdx.x * blockDim.x + threadIdx.x;
  __bf16* qw = (__bf16*)(ws + WS_QKVW);
  __bf16* pw = (__bf16*)(ws + WS_PROJW);
  float* bias = (float*)(ws + WS_BIAS);
  if (i < 288 * 96) qw[i] = (__bf16)qkv_w[i];
  int j = i - 288 * 96;
  if (j >= 0 && j < 96 * 96) pw[j] = (__bf16)proj_w[j];
  int t = i - (288 * 96 + 96 * 96);
  if (t >= 0 && t < HEADS * 16 * 64 * 4) {
    int r = t & 3;
    int lane = (t >> 2) & 63;
    int ba = (t >> 8) & 15;
    int h = t >> 12;
    int bq = ba >> 2, a = ba & 3;
    int l16 = lane & 15, lq = lane >> 4;
    int qrow = 16 * bq + l16;
    int kcol = 16 * a + 4 * lq + r;
    bias[t] = rpb[rpi[qrow * 64 + kcol] * HEADS + h];
  }
}

// r14: TWO windows per block as TWO SEPARATE 6-wave groups (768 threads,
// 12 waves; wave w -> window w/6, head w%6). Each wave runs the r9 body
// VERBATIM — identical ~60-VGPR footprint, ZERO cross-window register state
// (r11/r12/r13 all spilled from exactly that). Purpose: r4/r8/r9 plateau at
// ~50 windows/us with only ~1.6 blocks/CU resident while r6/r7 (slower waves)
// reached 42-67% occupancy -> steady-state co-residency tracks block arrival
// rate. Doubling waves per dispatched block tests & exploits that directly.
// LDS: per-window region 6656 bf16 (xfrag 6144 overlaid by ao[64][104]);
// total 26624 B. 3 barriers, now spanning 12 waves (both windows convoy —
// harmless, they're symmetric).
// LAUNCH BOUNDS lesson (r3/r6/r7/r11-13): arch-VGPR cliff ~64 under MFMA;
// keep the per-wave body at r9's measured 60.
template <bool USE_WS>
__global__ __launch_bounds__(768, 4) void win_attn(
    const float* __restrict__ x,
    const int* __restrict__ rpi,
    const float* __restrict__ qkv_w,
    const float* __restrict__ qkv_b,
    const float* __restrict__ proj_w,
    const float* __restrict__ proj_b,
    const float* __restrict__ rpb,
    const char* __restrict__ ws,
    float* __restrict__ out) {
  __shared__ __align__(16) __bf16 lds[2 * 6656];

  const int tid = (int)threadIdx.x;
  const int wv = tid >> 6;      // 0..11
  const int win = wv / 6;       // 0,1: window within block
  const int h = wv - 6 * win;   // head
  const int lane = tid & 63;
  const int l16 = lane & 15;
  const int lq = lane >> 4;
  const int b = 2 * (int)blockIdx.x + win;

  __bf16* xfrag = lds + win * 6656;  // 12 frags * 512 bf16 = 12288 B
  __bf16* ao = xfrag;                // [64][104] overlay (post-barrier)

  const float* xw = x + (size_t)b * (NTOK * DIM);
  const __bf16* qwb = (const __bf16*)(ws + WS_QKVW);
  const __bf16* pwb = (const __bf16*)(ws + WS_PROJW);
  const float4* bias4 = (const float4*)(ws + WS_BIAS) + (h << 10);

  // ---- stage this window's x fragments (wave's head h does 2h, 2h+1) ----
#pragma unroll
  for (int ff = 0; ff < 2; ++ff) {
    const int f = 2 * h + ff;
    const int mt = f / 3, ks = f - 3 * mt;
    bf16x8 v = cvt8(xw + (16 * mt + l16) * DIM + 32 * ks + 8 * lq);
    *(bf16x8*)(xfrag + (f * 64 + lane) * 8) = v;
  }
  __syncthreads();

#define XV(mt, ks) (*(const bf16x8*)(xfrag + (((mt) * 3 + (ks)) * 64 + lane) * 8))

  // ---- K phase: D = Wk * X^T; D-frag (feat=4lq+r, tok=l16) stays in regs ----
  bf16x4 kb[4];
  {
    const int frow = (HEADS + h) * 16;
    bf16x8 wb[3];
#pragma unroll
    for (int ks = 0; ks < 3; ++ks) {
      if constexpr (USE_WS)
        wb[ks] = *(const bf16x8*)(qwb + (frow + l16) * 96 + 32 * ks + 8 * lq);
      else
        wb[ks] = cvt8(qkv_w + (frow + l16) * 96 + 32 * ks + 8 * lq);
    }
    const float4 kb4 = *(const float4*)(qkv_b + frow + 4 * lq);
    const float kbv[4] = {kb4.x, kb4.y, kb4.z, kb4.w};
#pragma unroll
    for (int mt = 0; mt < 4; ++mt) {
      f32x4 acc = {0.f, 0.f, 0.f, 0.f};
#pragma unroll
      for (int ks = 0; ks < 3; ++ks) acc = mfma32(wb[ks], XV(mt, ks), acc);
#pragma unroll
      for (int r = 0; r < 4; ++r) kb[mt][r] = (__bf16)(acc[r] + kbv[r]);
    }
  }

  // ---- Q phase: D = Wq * X^T (scaled); registers only ----
  bf16x4 qv4[4];
  {
    const int frow = h * 16;
    bf16x8 wb[3];
#pragma unroll
    for (int ks = 0; ks < 3; ++ks) {
      if constexpr (USE_WS)
        wb[ks] = *(const bf16x8*)(qwb + (frow + l16) * 96 + 32 * ks + 8 * lq);
      else
        wb[ks] = cvt8(qkv_w + (frow + l16) * 96 + 32 * ks + 8 * lq);
    }
    const float4 qb4 = *(const float4*)(qkv_b + frow + 4 * lq);
    const float qbv[4] = {qb4.x, qb4.y, qb4.z, qb4.w};
#pragma unroll
    for (int mt = 0; mt < 4; ++mt) {
      f32x4 acc = {0.f, 0.f, 0.f, 0.f};
#pragma unroll
      for (int ks = 0; ks < 3; ++ks) acc = mfma32(wb[ks], XV(mt, ks), acc);
#pragma unroll
      for (int r = 0; r < 4; ++r) qv4[mt][r] = (__bf16)((acc[r] + qbv[r]) * 0.25f);
    }
  }

  // ---- V phase: D = X * Wv^T; D-frag for mt=a IS the PV B-frag chunk a ----
  bf16x4 vb4[4];
  {
    const int frow = (2 * HEADS + h) * 16;
    bf16x8 wb[3];
#pragma unroll
    for (int ks = 0; ks < 3; ++ks) {
      if constexpr (USE_WS)
        wb[ks] = *(const bf16x8*)(qwb + (frow + l16) * 96 + 32 * ks + 8 * lq);
      else
        wb[ks] = cvt8(qkv_w + (frow + l16) * 96 + 32 * ks + 8 * lq);
    }
    const float vb = qkv_b[frow + l16];
#pragma unroll
    for (int mt = 0; mt < 4; ++mt) {
      f32x4 acc = {0.f, 0.f, 0.f, 0.f};
#pragma unroll
      for (int ks = 0; ks < 3; ++ks) acc = mfma32(XV(mt, ks), wb[ks], acc);
#pragma unroll
      for (int r = 0; r < 4; ++r) vb4[mt][r] = (__bf16)(acc[r] + vb);
    }
  }
#undef XV
  // all waves done with xfrag before ao overlays it
  __syncthreads();

  // ---- attention per q-tile: pure register dataflow, no LDS, no drains ----
#pragma unroll
  for (int bq = 0; bq < 4; ++bq) {
    f32x4 s[4];
    if constexpr (USE_WS) {
#pragma unroll
      for (int a = 0; a < 4; ++a) {
        float4 t = bias4[(bq * 4 + a) * 64 + lane];
        s[a][0] = t.x; s[a][1] = t.y; s[a][2] = t.z; s[a][3] = t.w;
      }
    } else {
#pragma unroll
      for (int a = 0; a < 4; ++a)
#pragma unroll
        for (int r = 0; r < 4; ++r)
          s[a][r] = rpb[rpi[(16 * bq + l16) * 64 + 16 * a + 4 * lq + r] * HEADS + h];
    }

    // QK^T: S^T = K * Q^T with bias as C-init (4 chained mfma16k)
#pragma unroll
    for (int a = 0; a < 4; ++a) s[a] = mfma16k(kb[a], qv4[bq], s[a]);

    // unnormalized softmax (|logits|<<1 -> exp direct); tsum from the
    // bf16-rounded P so numerator/denominator match (r9 lesson)
    float tp[4];
    bf16x4 pa[4];
#pragma unroll
    for (int a = 0; a < 4; ++a) {
      float t0 = 0.f;
#pragma unroll
      for (int r = 0; r < 4; ++r) {
        const __bf16 pe = (__bf16)__expf(s[a][r]);
        pa[a][r] = pe;
        t0 += (float)pe;
      }
      tp[a] = t0;
    }
    float tsum = (tp[0] + tp[1]) + (tp[2] + tp[3]);
    tsum += __shfl_xor(tsum, 16);
    tsum += __shfl_xor(tsum, 32);  // rcp latency hides under PV below

    // PV: O_tile = sum_a P_chunk[a] * V_chunk[a], all in registers
    f32x4 oacc = {0.f, 0.f, 0.f, 0.f};
#pragma unroll
    for (int a = 0; a < 4; ++a) oacc = mfma16k(pa[a], vb4[a], oacc);

    const float rv = 1.0f / tsum;  // normalize after PV (linearity)
#pragma unroll
    for (int r = 0; r < 4; ++r)
      ao[(16 * bq + 4 * lq + r) * 104 + 16 * h + l16] = (__bf16)(oacc[r] * rv);
  }
  __syncthreads();  // ao writes -> cross-head proj reads

  // ---- proj ----
  bf16x8 wpb[3];
#pragma unroll
  for (int ks = 0; ks < 3; ++ks) {
    if constexpr (USE_WS)
      wpb[ks] = *(const bf16x8*)(pwb + (16 * h + l16) * 96 + 32 * ks + 8 * lq);
    else
      wpb[ks] = cvt8(proj_w + (16 * h + l16) * 96 + 32 * ks + 8 * lq);
  }
  const float pb2 = proj_b[16 * h + l16];
  float* outw = out + (size_t)b * (NTOK * DIM);
#pragma unroll
  for (int mt = 0; mt < 4; ++mt) {
    f32x4 acc = {0.f, 0.f, 0.f, 0.f};
#pragma unroll
    for (int ks = 0; ks < 3; ++ks) {
      bf16x8 aa = *(const bf16x8*)(ao + (16 * mt + l16) * 104 + 32 * ks + 8 * lq);
      acc = mfma32(aa, wpb[ks], acc);
    }
#pragma unroll
    for (int r = 0; r < 4; ++r)
      outw[(16 * mt + 4 * lq + r) * 96 + 16 * h + l16] = acc[r] + pb2;
  }
}

extern "C" void kernel_launch(void* const* d_in, const int* in_sizes, int n_in,
                              void* d_out, int out_size, void* d_ws, size_t ws_size,
                              hipStream_t stream) {
  const float* x      = (const float*)d_in[0];
  const int*   rpi    = (const int*)d_in[1];
  const float* qkv_w  = (const float*)d_in[2];
  const float* qkv_b  = (const float*)d_in[3];
  const float* proj_w = (const float*)d_in[4];
  const float* proj_b = (const float*)d_in[5];
  const float* rpb    = (const float*)d_in[6];
  float* out = (float*)d_out;

  if (ws_size >= (size_t)WS_TOTAL) {
    prep_kernel<<<240, 256, 0, stream>>>(qkv_w, proj_w, rpb, rpi, (char*)d_ws);
    win_attn<true><<<NWIN / 2, 768, 0, stream>>>(x, rpi, qkv_w, qkv_b, proj_w,
                                                 proj_b, rpb, (const char*)d_ws,
                                                 out);
  } else {
    win_attn<false><<<NWIN / 2, 768, 0, stream>>>(x, rpi, qkv_w, qkv_b, proj_w,
                                                  proj_b, rpb,
                                                  (const char*)d_ws, out);
  }
}

// Round 15
// 81.550 us; speedup vs baseline: 3.7936x; 1.0648x over previous
//
#include <hip/hip_runtime.h>

#define NWIN 4096
#define DIM 96
#define HEADS 6
#define NTOK 64

typedef __bf16 bf16x8 __attribute__((ext_vector_type(8)));
typedef __bf16 bf16x4 __attribute__((ext_vector_type(4)));
typedef short  s16x4  __attribute__((ext_vector_type(4)));
typedef float  f32x4  __attribute__((ext_vector_type(4)));

// d_ws layout
#define WS_QKVW 0                   // 288*96 bf16 = 55296 B
#define WS_PROJW 55296              // 96*96 bf16  = 18432 B
#define WS_BIAS 73728               // 6*16*64 float4 = 98304 B (frag-ordered)
#define WS_TOTAL 172032

__device__ __forceinline__ f32x4 mfma32(bf16x8 a, bf16x8 b, f32x4 c) {
  return __builtin_amdgcn_mfma_f32_16x16x32_bf16(a, b, c, 0, 0, 0);
}
// K=16 MFMA. Fragment alignment facts (verified r7-r9):
//  * A/B fragment lane(l16,lq) holds row/col=l16, k=4*lq+e  — identical to
//    the W*X^T D-fragment (row=4lq+r, col=l16), so K,Q stay in registers.
//  * QK^T output s[a] = S[q=l16][kv=16a+4lq+r] — IS the PV A-frag chunk a.
//  * V-phase D-frag for mt=a IS the PV B-frag chunk a.
//  => K,Q,V,P all stay in registers; no LDS in the attention core.
__device__ __forceinline__ f32x4 mfma16k(bf16x4 a, bf16x4 b, f32x4 c) {
  return __builtin_amdgcn_mfma_f32_16x16x16bf16_1k(
      __builtin_bit_cast(s16x4, a), __builtin_bit_cast(s16x4, b), c, 0, 0, 0);
}

__device__ __forceinline__ bf16x8 cvt8(const float* p) {
  const float4* q = (const float4*)p;
  float4 a = q[0];
  float4 b = q[1];
  bf16x8 r;
  r[0] = (__bf16)a.x; r[1] = (__bf16)a.y; r[2] = (__bf16)a.z; r[3] = (__bf16)a.w;
  r[4] = (__bf16)b.x; r[5] = (__bf16)b.y; r[6] = (__bf16)b.z; r[7] = (__bf16)b.w;
  return r;
}

// Pre-pass: weights -> bf16; bias gathered into MFMA-fragment order:
// bias[((h*16 + bq*4 + a)*64 + lane)*4 + r] = rpb[rpi[qrow*64+kcol]*6+h]
// with qrow = 16*bq + (lane&15), kcol = 16*a + 4*(lane>>4) + r.
__global__ void prep_kernel(const float* __restrict__ qkv_w,
                            const float* __restrict__ proj_w,
                            const float* __restrict__ rpb,
                            const int* __restrict__ rpi,
                            char* __restrict__ ws) {
  int i = blockIdx.x * blockDim.x + threadIdx.x;
  __bf16* qw = (__bf16*)(ws + WS_QKVW);
  __bf16* pw = (__bf16*)(ws + WS_PROJW);
  float* bias = (float*)(ws + WS_BIAS);
  if (i < 288 * 96) qw[i] = (__bf16)qkv_w[i];
  int j = i - 288 * 96;
  if (j >= 0 && j < 96 * 96) pw[j] = (__bf16)proj_w[j];
  int t = i - (288 * 96 + 96 * 96);
  if (t >= 0 && t < HEADS * 16 * 64 * 4) {
    int r = t & 3;
    int lane = (t >> 2) & 63;
    int ba = (t >> 8) & 15;
    int h = t >> 12;
    int bq = ba >> 2, a = ba & 3;
    int l16 = lane & 15, lq = lane >> 4;
    int qrow = 16 * bq + l16;
    int kcol = 16 * a + 4 * lq + r;
    bias[t] = rpb[rpi[qrow * 64 + kcol] * HEADS + h];
  }
}

// r15: FEWER, FATTER WAVES. Empirical law from r4/r8/r9/r14: sustained wave
// rate is ~300 waves/us regardless of block shape (blocks/us varied 2x) —
// so cut total waves 3x: block = 128 threads (2 waves), one window; wave wv
// runs heads {wv, wv+2, wv+4} SEQUENTIALLY through the verbatim r9 per-head
// body. #pragma unroll 1 on the head loop so the compiler cannot interleave
// head pipelines (that interleaving is what spilled r11/r12/r13); no FP
// state is loop-carried -> register peak stays at r9's ~60.
// LDS: xfrag 12288 B and ao 13312 B DISJOINT (xfrag must live across all 3
// heads) = 25600 B -> 6 blocks/CU. Only 2 barriers per window.
// Proj: 3 column-tiles per wave, ao re-read per tile (never hoisted — r10).
template <bool USE_WS>
__global__ __launch_bounds__(128, 4) void win_attn(
    const float* __restrict__ x,
    const int* __restrict__ rpi,
    const float* __restrict__ qkv_w,
    const float* __restrict__ qkv_b,
    const float* __restrict__ proj_w,
    const float* __restrict__ proj_b,
    const float* __restrict__ rpb,
    const char* __restrict__ ws,
    float* __restrict__ out) {
  __shared__ __align__(16) __bf16 xfrag[6144];   // 12 frags * 512 bf16
  __shared__ __align__(16) __bf16 ao[64 * 104];  // 13312 B

  const int tid = (int)threadIdx.x;
  const int wv = tid >> 6;  // 0..1
  const int lane = tid & 63;
  const int l16 = lane & 15;
  const int lq = lane >> 4;
  const int b = (int)blockIdx.x;

  const float* xw = x + (size_t)b * (NTOK * DIM);
  const __bf16* qwb = (const __bf16*)(ws + WS_QKVW);
  const __bf16* pwb = (const __bf16*)(ws + WS_PROJW);

  // ---- stage x fragments (wave wv does frags 6wv..6wv+5; mt,ks static) ----
#pragma unroll
  for (int ff = 0; ff < 6; ++ff) {
    const int mt = 2 * wv + ff / 3;     // ff/3 compile-time
    const int ks = ff % 3;              // compile-time
    const int f = 6 * wv + ff;
    bf16x8 v = cvt8(xw + (16 * mt + l16) * DIM + 32 * ks + 8 * lq);
    *(bf16x8*)(xfrag + (f * 64 + lane) * 8) = v;
  }
  __syncthreads();

#define XV(mt, ks) (*(const bf16x8*)(xfrag + (((mt) * 3 + (ks)) * 64 + lane) * 8))

  // ---- 3 heads sequentially per wave; NO unroll (register discipline) ----
#pragma unroll 1
  for (int hh = 0; hh < 3; ++hh) {
    const int h = wv + 2 * hh;

    // K phase: D = Wk * X^T; D-frag (feat=4lq+r, tok=l16) stays in regs
    bf16x4 kb[4];
    {
      const int frow = (HEADS + h) * 16;
      bf16x8 wb[3];
#pragma unroll
      for (int ks = 0; ks < 3; ++ks) {
        if constexpr (USE_WS)
          wb[ks] = *(const bf16x8*)(qwb + (frow + l16) * 96 + 32 * ks + 8 * lq);
        else
          wb[ks] = cvt8(qkv_w + (frow + l16) * 96 + 32 * ks + 8 * lq);
      }
      const float4 kb4 = *(const float4*)(qkv_b + frow + 4 * lq);
      const float kbv[4] = {kb4.x, kb4.y, kb4.z, kb4.w};
#pragma unroll
      for (int mt = 0; mt < 4; ++mt) {
        f32x4 acc = {0.f, 0.f, 0.f, 0.f};
#pragma unroll
        for (int ks = 0; ks < 3; ++ks) acc = mfma32(wb[ks], XV(mt, ks), acc);
#pragma unroll
        for (int r = 0; r < 4; ++r) kb[mt][r] = (__bf16)(acc[r] + kbv[r]);
      }
    }

    // Q phase: D = Wq * X^T (scaled); registers only
    bf16x4 qv4[4];
    {
      const int frow = h * 16;
      bf16x8 wb[3];
#pragma unroll
      for (int ks = 0; ks < 3; ++ks) {
        if constexpr (USE_WS)
          wb[ks] = *(const bf16x8*)(qwb + (frow + l16) * 96 + 32 * ks + 8 * lq);
        else
          wb[ks] = cvt8(qkv_w + (frow + l16) * 96 + 32 * ks + 8 * lq);
      }
      const float4 qb4 = *(const float4*)(qkv_b + frow + 4 * lq);
      const float qbv[4] = {qb4.x, qb4.y, qb4.z, qb4.w};
#pragma unroll
      for (int mt = 0; mt < 4; ++mt) {
        f32x4 acc = {0.f, 0.f, 0.f, 0.f};
#pragma unroll
        for (int ks = 0; ks < 3; ++ks) acc = mfma32(wb[ks], XV(mt, ks), acc);
#pragma unroll
        for (int r = 0; r < 4; ++r)
          qv4[mt][r] = (__bf16)((acc[r] + qbv[r]) * 0.25f);
      }
    }

    // V phase: D = X * Wv^T; D-frag for mt=a IS the PV B-frag chunk a
    bf16x4 vb4[4];
    {
      const int frow = (2 * HEADS + h) * 16;
      bf16x8 wb[3];
#pragma unroll
      for (int ks = 0; ks < 3; ++ks) {
        if constexpr (USE_WS)
          wb[ks] = *(const bf16x8*)(qwb + (frow + l16) * 96 + 32 * ks + 8 * lq);
        else
          wb[ks] = cvt8(qkv_w + (frow + l16) * 96 + 32 * ks + 8 * lq);
      }
      const float vb = qkv_b[frow + l16];
#pragma unroll
      for (int mt = 0; mt < 4; ++mt) {
        f32x4 acc = {0.f, 0.f, 0.f, 0.f};
#pragma unroll
        for (int ks = 0; ks < 3; ++ks) acc = mfma32(XV(mt, ks), wb[ks], acc);
#pragma unroll
        for (int r = 0; r < 4; ++r) vb4[mt][r] = (__bf16)(acc[r] + vb);
      }
    }

    // attention per q-tile: pure register dataflow
    const float4* bias4 = (const float4*)(ws + WS_BIAS) + (h << 10);
#pragma unroll
    for (int bq = 0; bq < 4; ++bq) {
      f32x4 s[4];
      if constexpr (USE_WS) {
#pragma unroll
        for (int a = 0; a < 4; ++a) {
          float4 t = bias4[(bq * 4 + a) * 64 + lane];
          s[a][0] = t.x; s[a][1] = t.y; s[a][2] = t.z; s[a][3] = t.w;
        }
      } else {
#pragma unroll
        for (int a = 0; a < 4; ++a)
#pragma unroll
          for (int r = 0; r < 4; ++r)
            s[a][r] = rpb[rpi[(16 * bq + l16) * 64 + 16 * a + 4 * lq + r] *
                              HEADS + h];
      }

      // QK^T: S^T = K * Q^T with bias as C-init
#pragma unroll
      for (int a = 0; a < 4; ++a) s[a] = mfma16k(kb[a], qv4[bq], s[a]);

      // unnormalized softmax (|logits|<<1 -> exp direct); tsum from the
      // bf16-rounded P so numerator/denominator match (r9 lesson)
      float tp[4];
      bf16x4 pa[4];
#pragma unroll
      for (int a = 0; a < 4; ++a) {
        float t0 = 0.f;
#pragma unroll
        for (int r = 0; r < 4; ++r) {
          const __bf16 pe = (__bf16)__expf(s[a][r]);
          pa[a][r] = pe;
          t0 += (float)pe;
        }
        tp[a] = t0;
      }
      float tsum = (tp[0] + tp[1]) + (tp[2] + tp[3]);
      tsum += __shfl_xor(tsum, 16);
      tsum += __shfl_xor(tsum, 32);  // rcp latency hides under PV

      // PV: O_tile = sum_a P_chunk[a] * V_chunk[a], all in registers
      f32x4 oacc = {0.f, 0.f, 0.f, 0.f};
#pragma unroll
      for (int a = 0; a < 4; ++a) oacc = mfma16k(pa[a], vb4[a], oacc);

      const float rv = 1.0f / tsum;  // normalize after PV (linearity)
#pragma unroll
      for (int r = 0; r < 4; ++r)
        ao[(16 * bq + 4 * lq + r) * 104 + 16 * h + l16] =
            (__bf16)(oacc[r] * rv);
    }
  }
#undef XV
  __syncthreads();  // ao complete (xfrag disjoint: no overlay hazard)

  // ---- proj: 3 column-tiles per wave (c = wv, wv+2, wv+4); no hoisting ----
  float* outw = out + (size_t)b * (NTOK * DIM);
#pragma unroll 1
  for (int cc = 0; cc < 3; ++cc) {
    const int c = wv + 2 * cc;
    bf16x8 wpb[3];
#pragma unroll
    for (int ks = 0; ks < 3; ++ks) {
      if constexpr (USE_WS)
        wpb[ks] = *(const bf16x8*)(pwb + (16 * c + l16) * 96 + 32 * ks + 8 * lq);
      else
        wpb[ks] = cvt8(proj_w + (16 * c + l16) * 96 + 32 * ks + 8 * lq);
    }
    const float pb2 = proj_b[16 * c + l16];
#pragma unroll
    for (int mt = 0; mt < 4; ++mt) {
      f32x4 acc = {0.f, 0.f, 0.f, 0.f};
#pragma unroll
      for (int ks = 0; ks < 3; ++ks) {
        bf16x8 aa =
            *(const bf16x8*)(ao + (16 * mt + l16) * 104 + 32 * ks + 8 * lq);
        acc = mfma32(aa, wpb[ks], acc);
      }
#pragma unroll
      for (int r = 0; r < 4; ++r)
        outw[(16 * mt + 4 * lq + r) * 96 + 16 * c + l16] = acc[r] + pb2;
    }
  }
}

extern "C" void kernel_launch(void* const* d_in, const int* in_sizes, int n_in,
                              void* d_out, int out_size, void* d_ws, size_t ws_size,
                              hipStream_t stream) {
  const float* x      = (const float*)d_in[0];
  const int*   rpi    = (const int*)d_in[1];
  const float* qkv_w  = (const float*)d_in[2];
  const float* qkv_b  = (const float*)d_in[3];
  const float* proj_w = (const float*)d_in[4];
  const float* proj_b = (const float*)d_in[5];
  const float* rpb    = (const float*)d_in[6];
  float* out = (float*)d_out;

  if (ws_size >= (size_t)WS_TOTAL) {
    prep_kernel<<<240, 256, 0, stream>>>(qkv_w, proj_w, rpb, rpi, (char*)d_ws);
    win_attn<true><<<NWIN, 128, 0, stream>>>(x, rpi, qkv_w, qkv_b, proj_w,
                                             proj_b, rpb, (const char*)d_ws,
                                             out);
  } else {
    win_attn<false><<<NWIN, 128, 0, stream>>>(x, rpi, qkv_w, qkv_b, proj_w,
                                              proj_b, rpb, (const char*)d_ws,
                                              out);
  }
}